// Round 9
// baseline (913.507 us; speedup 1.0000x reference)
//
#include <hip/hip_runtime.h>
#include <hip/hip_bf16.h>
#include <stddef.h>

// Problem constants
constexpr int E_ = 8;
constexpr int C_ = 1024;
constexpr int M_ = 2048;
constexpr int H_ = 8192;
constexpr int O_ = 2048;

typedef __bf16 bf16;
typedef __bf16 bf16x4 __attribute__((ext_vector_type(4)));
typedef __bf16 bf16x8 __attribute__((ext_vector_type(8)));
typedef float  f32x4  __attribute__((ext_vector_type(4)));

#define GLOAD16(src, dst)                                                        \
    __builtin_amdgcn_global_load_lds(                                            \
        (const __attribute__((address_space(1))) void*)(src),                    \
        (__attribute__((address_space(3))) void*)(dst), 16, 0, 0)

#define BARRIER()  __builtin_amdgcn_s_barrier()
#define LGKM0()    do { asm volatile("s_waitcnt lgkmcnt(0)" ::: "memory");       \
                        __builtin_amdgcn_sched_barrier(0); } while (0)
#define VMCNT(n)   asm volatile("s_waitcnt vmcnt(" #n ")" ::: "memory")

// ---------------------------------------------------------------------------
// fp32 -> bf16 convert (grid-stride, 64B-read/32B-write per lane per iter)
// ---------------------------------------------------------------------------
__global__ __launch_bounds__(256)
void cvt_f32_bf16(const float* __restrict__ in, bf16* __restrict__ out, size_t n)
{
    size_t i = ((size_t)blockIdx.x * blockDim.x + threadIdx.x) * 16;
    const size_t stride = (size_t)gridDim.x * blockDim.x * 16;
    for (; i < n; i += stride) {
        f32x4 v0 = *(const f32x4*)(in + i);
        f32x4 v1 = *(const f32x4*)(in + i + 4);
        f32x4 v2 = *(const f32x4*)(in + i + 8);
        f32x4 v3 = *(const f32x4*)(in + i + 12);
        bf16x8 o0, o1;
#pragma unroll
        for (int j = 0; j < 4; ++j) {
            o0[j] = (bf16)v0[j]; o0[j + 4] = (bf16)v1[j];
            o1[j] = (bf16)v2[j]; o1[j + 4] = (bf16)v3[j];
        }
        *(bf16x8*)(out + i)     = o0;
        *(bf16x8*)(out + i + 8) = o1;
    }
}

// ---------------------------------------------------------------------------
// 256x256-tile 8-phase GEMM, BK=64, 128 KiB LDS, 8 waves (r3-proven).
// Both A,B row-major K-contiguous bf16. Used for gemm1 (K=2048).
// ---------------------------------------------------------------------------
template<int KDIM, bool RELU_BF16>
__global__ __launch_bounds__(512, 2)
void gemm256(const bf16* __restrict__ A, const bf16* __restrict__ B,
             const float* __restrict__ bias, void* __restrict__ OutP,
             int nBM, int nBN)
{
    extern __shared__ char smem[];                  // 131072 B
    constexpr int K2  = KDIM * 2;
    constexpr int NIT = KDIM / 128;

    const int tid  = threadIdx.x;
    const int lane = tid & 63;
    const int wid  = tid >> 6;
    const int wr = wid >> 2, wc = wid & 3;
    const int fr = lane & 15, fq = lane >> 4;

    const int nwg = gridDim.x;
    const int cpx = nwg >> 3;
    const int b0  = blockIdx.x;
    const int wg  = (b0 & 7) * cpx + (b0 >> 3);
    const int per_e = nBM * nBN;
    const int e  = wg / per_e;
    const int rr = wg - e * per_e;
    const int bn = rr / nBM;
    const int bm = rr - bn * nBM;
    const int MROWS = nBM * 256;
    const int NROWS = nBN * 256;

    const char* Apan = (const char*)(A + (size_t)e * MROWS * KDIM + (size_t)bm * 256 * KDIM);
    const char* Bpan = (const char*)(B + (size_t)e * NROWS * KDIM + (size_t)bn * 256 * KDIM);

    const int r0  = tid >> 3;
    const int wsw = ((tid & 7) << 4) ^ ((r0 & 7) << 4);

    auto stageA = [&](int gk, int comp) {
        char* lds = smem + (gk & 1) * 65536 + comp * 16384 + tid * 16;
        const char* src = Apan + (size_t)((comp << 7) + r0) * K2 + (size_t)gk * 128 + wsw;
        GLOAD16(src, lds);
        GLOAD16(src + (size_t)64 * K2, lds + 8192);
    };
    auto stageB = [&](int gk, int comp2) {
        char* lds = smem + (gk & 1) * 65536 + 32768 + comp2 * 16384 + tid * 16;
        const char* src = Bpan + (size_t)((comp2 << 7) + r0) * K2 + (size_t)gk * 128 + wsw;
        GLOAD16(src, lds);
        GLOAD16(src + (size_t)64 * K2, lds + 8192);
    };

    const int frq = fr & 7;
    const int cA0 = ((fq    ) ^ frq) << 4;
    const int cA1 = ((4 | fq) ^ frq) << 4;
    const int aoff = wr * 16384 + fr * 128;
    const int boff = 32768 + (wc >> 1) * 16384 + (wc & 1) * 8192 + fr * 128;

    bf16x8 av[4][2];
    bf16x8 bv[4][2];
    f32x4 acc[8][4];
#pragma unroll
    for (int m = 0; m < 8; ++m)
#pragma unroll
        for (int n = 0; n < 4; ++n) acc[m][n] = (f32x4){0.f, 0.f, 0.f, 0.f};

    auto loadA = [&](const char* base, int mh) {
#pragma unroll
        for (int mm = 0; mm < 4; ++mm) {
            const char* p = base + aoff + (mh * 4 + mm) * 2048;
            av[mm][0] = *(const bf16x8*)(p + cA0);
            av[mm][1] = *(const bf16x8*)(p + cA1);
        }
    };
    auto loadB = [&](const char* base, int nh) {
#pragma unroll
        for (int nn = 0; nn < 2; ++nn) {
            const char* p = base + boff + (nh * 2 + nn) * 2048;
            bv[nh * 2 + nn][0] = *(const bf16x8*)(p + cA0);
            bv[nh * 2 + nn][1] = *(const bf16x8*)(p + cA1);
        }
    };
    auto mmaq = [&](int mh, int nh) {
        __builtin_amdgcn_s_setprio(1);
#pragma unroll
        for (int mm = 0; mm < 4; ++mm)
#pragma unroll
            for (int nn = 0; nn < 2; ++nn) {
                const int m = mh * 4 + mm, n = nh * 2 + nn;
                acc[m][n] = __builtin_amdgcn_mfma_f32_16x16x32_bf16(av[mm][0], bv[n][0], acc[m][n], 0, 0, 0);
                acc[m][n] = __builtin_amdgcn_mfma_f32_16x16x32_bf16(av[mm][1], bv[n][1], acc[m][n], 0, 0, 0);
            }
        __builtin_amdgcn_s_setprio(0);
    };

    stageB(0, 0); stageB(0, 1); stageA(0, 0); stageA(0, 1);
    stageB(1, 0); stageB(1, 1);
    VMCNT(4);
    BARRIER();

    for (int t = 0; t < NIT; ++t) {
        const bool nl = (t + 1 < NIT);
        const char* d0b = smem;
        const char* d1b = smem + 65536;
        const int ga = 2 * t + 1;
        const int gb = 2 * t + 2;
        const int gc = 2 * t + 3;

        loadB(d0b, 0); loadA(d0b, 0);       // ph0
        stageA(ga, 0);
        BARRIER(); LGKM0();
        mmaq(0, 0);
        BARRIER();

        loadB(d0b, 1);                      // ph1
        stageA(ga, 1);
        BARRIER(); LGKM0();
        mmaq(0, 1);
        BARRIER();

        loadA(d0b, 1);                      // ph2
        if (nl) stageB(gb, 0);
        BARRIER(); LGKM0();
        mmaq(1, 1);
        BARRIER();

        if (nl) stageB(gb, 1);              // ph3
        BARRIER(); LGKM0();
        mmaq(1, 0);
        if (nl) { VMCNT(4); } else { VMCNT(0); }
        BARRIER();

        loadB(d1b, 0); loadA(d1b, 0);       // ph4
        if (nl) stageA(gb, 0);
        BARRIER(); LGKM0();
        mmaq(0, 0);
        BARRIER();

        loadB(d1b, 1);                      // ph5
        if (nl) stageA(gb, 1);
        BARRIER(); LGKM0();
        mmaq(0, 1);
        BARRIER();

        loadA(d1b, 1);                      // ph6
        if (nl) stageB(gc, 0);
        BARRIER(); LGKM0();
        mmaq(1, 1);
        BARRIER();

        if (nl) stageB(gc, 1);              // ph7
        BARRIER(); LGKM0();
        mmaq(1, 0);
        if (nl) {
            VMCNT(4);
            BARRIER();
        }
    }

    const int gr0 = bm * 256 + wr * 128;
    const int gc0 = bn * 256 + wc * 64;
    if constexpr (RELU_BF16) {
        bf16* Out = (bf16*)OutP;
#pragma unroll
        for (int n = 0; n < 4; ++n) {
            const int col = gc0 + n * 16 + fr;
            const float bb = bias[(size_t)e * NROWS + col];
#pragma unroll
            for (int m = 0; m < 8; ++m)
#pragma unroll
                for (int j = 0; j < 4; ++j) {
                    float v = acc[m][n][j] + bb;
                    v = v > 0.f ? v : 0.f;
                    const int row = gr0 + m * 16 + fq * 4 + j;
                    Out[((size_t)e * MROWS + row) * NROWS + col] = (bf16)v;
                }
        }
    } else {
        float* Out = (float*)OutP;
#pragma unroll
        for (int n = 0; n < 4; ++n) {
            const int col = gc0 + n * 16 + fr;
            const float bb = bias[(size_t)e * NROWS + col];
#pragma unroll
            for (int m = 0; m < 8; ++m)
#pragma unroll
                for (int j = 0; j < 4; ++j) {
                    const int row = gr0 + m * 16 + fq * 4 + j;
                    Out[((size_t)e * MROWS + row) * NROWS + col] = acc[m][n][j] + bb;
                }
        }
    }
}

// ---------------------------------------------------------------------------
// TN variant for gemm2: out[c][o] = sum_h y1[c][h] * w2[h][o] + b2[o].
// A = y1 bf16 K-contiguous (staged exactly as gemm256). B = w2 NATIVE fp32
// [H][O] (K=h is the slow dim): per half-tile each thread loads a 4h x 4o
// fp32 block (coalesced along o), converts (compiler-fused cvt_pk) and
// ds_write_b64's the 4x4 transpose into the IDENTICAL swizzled [o][h] LDS
// layout gemm256's frag reads use. vmcnt engineering (r6 semantics, reg-fix):
// B-loads issued ph0/ph1 (2-3-phase lead >> HBM latency, issued BEFORE the
// same-phase stageA so auto-waits never force-retire younger A prefetches);
// writes at ph2/ph3; only 16+16 extra VGPRs live. VMCNT(0)@ph3/ph7 waits only
// 2-phase-old stageA. LDS hazards: B(gb) region (buf0 B) last read ph1,
// written ph2/ph3 (>=1 barrier later); writes drain at own-phase LGKM0
// before the closing barrier; first cross-wave read is next-iter ph0.
// ---------------------------------------------------------------------------
__global__ __launch_bounds__(512, 2)
void gemm2tn(const bf16* __restrict__ A, const float* __restrict__ W2,
             const float* __restrict__ bias, float* __restrict__ Out,
             int nBM, int nBN)
{
    extern __shared__ char smem[];                  // 131072 B
    constexpr int KDIM = H_;
    constexpr int K2   = KDIM * 2;
    constexpr int NIT  = KDIM / 128;                // 64

    const int tid  = threadIdx.x;
    const int lane = tid & 63;
    const int wid  = tid >> 6;
    const int wr = wid >> 2, wc = wid & 3;
    const int fr = lane & 15, fq = lane >> 4;

    const int nwg = gridDim.x;
    const int cpx = nwg >> 3;
    const int b0  = blockIdx.x;
    const int wg  = (b0 & 7) * cpx + (b0 >> 3);
    const int per_e = nBM * nBN;
    const int e  = wg / per_e;
    const int rr = wg - e * per_e;
    const int bn = rr / nBM;
    const int bm = rr - bn * nBM;      // bm fastest: 4 wgs sharing the fp32
                                       // B panel are consecutive -> same XCD
    const int MROWS = nBM * 256;
    const int NROWS = nBN * 256;

    const char*  Apan = (const char*)(A + (size_t)e * MROWS * KDIM + (size_t)bm * 256 * KDIM);
    const float* W2e  = W2 + (size_t)e * (size_t)H_ * O_;
    const int    bnCol = bn * 256;

    const int r0  = tid >> 3;
    const int wsw = ((tid & 7) << 4) ^ ((r0 & 7) << 4);

    auto stageA = [&](int gk, int comp) {
        char* lds = smem + (gk & 1) * 65536 + comp * 16384 + tid * 16;
        const char* src = Apan + (size_t)((comp << 7) + r0) * K2 + (size_t)gk * 128 + wsw;
        GLOAD16(src, lds);
        GLOAD16(src + (size_t)64 * K2, lds + 8192);
    };

    // B reg-staged transpose: thread -> o0 = (tid&31)*4 (0..124 within the
    // 128-o half), h0 = (tid>>5)*4 (0..60 within the 64-h K-tile).
    const int o0 = (tid & 31) * 4;
    const int h0 = (tid >> 5) * 4;
    const int hsub = ((h0 & 4) << 1);               // byte offset within chunk
    const int hchk = h0 >> 3;                       // 16B chunk index

    auto loadB32T = [&](int g, int comp2, f32x4* d) {
        const float* s = W2e + (size_t)(g * 64 + h0) * O_ + bnCol + comp2 * 128 + o0;
#pragma unroll
        for (int j = 0; j < 4; ++j) d[j] = *(const f32x4*)(s + (size_t)j * O_);
    };
    auto cvtwriteBT = [&](int g, int comp2, const f32x4* d) {
        char* rg = smem + (g & 1) * 65536 + 32768 + comp2 * 16384;
#pragma unroll
        for (int c = 0; c < 4; ++c) {
            bf16x4 w;
            w[0] = (bf16)d[0][c]; w[1] = (bf16)d[1][c];
            w[2] = (bf16)d[2][c]; w[3] = (bf16)d[3][c];
            const int r = o0 + c;
            *(bf16x4*)(rg + r * 128 + (((hchk ^ (r & 7)) << 4) | hsub)) = w;
        }
    };

    const int frq = fr & 7;
    const int cA0 = ((fq    ) ^ frq) << 4;
    const int cA1 = ((4 | fq) ^ frq) << 4;
    const int aoff = wr * 16384 + fr * 128;
    const int boff = 32768 + (wc >> 1) * 16384 + (wc & 1) * 8192 + fr * 128;

    bf16x8 av[4][2];
    bf16x8 bv[4][2];
    f32x4 acc[8][4];
#pragma unroll
    for (int m = 0; m < 8; ++m)
#pragma unroll
        for (int n = 0; n < 4; ++n) acc[m][n] = (f32x4){0.f, 0.f, 0.f, 0.f};

    auto loadA = [&](const char* base, int mh) {
#pragma unroll
        for (int mm = 0; mm < 4; ++mm) {
            const char* p = base + aoff + (mh * 4 + mm) * 2048;
            av[mm][0] = *(const bf16x8*)(p + cA0);
            av[mm][1] = *(const bf16x8*)(p + cA1);
        }
    };
    auto loadB = [&](const char* base, int nh) {
#pragma unroll
        for (int nn = 0; nn < 2; ++nn) {
            const char* p = base + boff + (nh * 2 + nn) * 2048;
            bv[nh * 2 + nn][0] = *(const bf16x8*)(p + cA0);
            bv[nh * 2 + nn][1] = *(const bf16x8*)(p + cA1);
        }
    };
    auto mmaq = [&](int mh, int nh) {
        __builtin_amdgcn_s_setprio(1);
#pragma unroll
        for (int mm = 0; mm < 4; ++mm)
#pragma unroll
            for (int nn = 0; nn < 2; ++nn) {
                const int m = mh * 4 + mm, n = nh * 2 + nn;
                acc[m][n] = __builtin_amdgcn_mfma_f32_16x16x32_bf16(av[mm][0], bv[n][0], acc[m][n], 0, 0, 0);
                acc[m][n] = __builtin_amdgcn_mfma_f32_16x16x32_bf16(av[mm][1], bv[n][1], acc[m][n], 0, 0, 0);
            }
        __builtin_amdgcn_s_setprio(0);
    };

    // prologue: tiles 0,1 resident (B via reg-transpose path); full drain once
    {
        f32x4 p0[4], p1[4];
        loadB32T(0, 0, p0); loadB32T(0, 1, p1);
        stageA(0, 0); stageA(0, 1);
        cvtwriteBT(0, 0, p0); cvtwriteBT(0, 1, p1);
        loadB32T(1, 0, p0); loadB32T(1, 1, p1);
        cvtwriteBT(1, 0, p0); cvtwriteBT(1, 1, p1);
        VMCNT(0);
        asm volatile("s_waitcnt lgkmcnt(0)" ::: "memory");
        BARRIER();
    }

    for (int t = 0; t < NIT; ++t) {
        const bool nl = (t + 1 < NIT);
        const char* d0b = smem;
        const char* d1b = smem + 65536;
        const int ga = 2 * t + 1;
        const int gb = 2 * t + 2;
        const int gc = 2 * t + 3;
        f32x4 d0[4], d1[4];

        // ---- K-tile a (dbuf0) ----
        loadB(d0b, 0); loadA(d0b, 0);       // ph0
        if (nl) loadB32T(gb, 0, d0);        // issued BEFORE stageA: queue order
        stageA(ga, 0);
        BARRIER(); LGKM0();
        mmaq(0, 0);
        BARRIER();

        loadB(d0b, 1);                      // ph1
        if (nl) loadB32T(gb, 1, d1);
        stageA(ga, 1);
        BARRIER(); LGKM0();
        mmaq(0, 1);
        BARRIER();

        loadA(d0b, 1);                      // ph2
        if (nl) cvtwriteBT(gb, 0, d0);      // auto-wait: ph0's B32 (2-ph old)
        BARRIER(); LGKM0();
        mmaq(1, 1);
        BARRIER();

        if (nl) cvtwriteBT(gb, 1, d1);      // ph3
        BARRIER(); LGKM0();
        mmaq(1, 0);
        VMCNT(0);                           // waits only 2-phase-old stageA(ga)
        BARRIER();

        // ---- K-tile b (dbuf1) ----
        loadB(d1b, 0); loadA(d1b, 0);       // ph4
        if (nl) { loadB32T(gc, 0, d0); stageA(gb, 0); }
        BARRIER(); LGKM0();
        mmaq(0, 0);
        BARRIER();

        loadB(d1b, 1);                      // ph5
        if (nl) { loadB32T(gc, 1, d1); stageA(gb, 1); }
        BARRIER(); LGKM0();
        mmaq(0, 1);
        BARRIER();

        loadA(d1b, 1);                      // ph6
        if (nl) cvtwriteBT(gc, 0, d0);
        BARRIER(); LGKM0();
        mmaq(1, 1);
        BARRIER();

        if (nl) cvtwriteBT(gc, 1, d1);      // ph7
        BARRIER(); LGKM0();
        mmaq(1, 0);
        if (nl) {
            VMCNT(0);
            BARRIER();
        }
    }

    // epilogue: + bias, fp32 store
    const int gr0 = bm * 256 + wr * 128;
    const int gc0 = bn * 256 + wc * 64;
#pragma unroll
    for (int n = 0; n < 4; ++n) {
        const int col = gc0 + n * 16 + fr;
        const float bb = bias[(size_t)e * NROWS + col];
#pragma unroll
        for (int m = 0; m < 8; ++m)
#pragma unroll
            for (int j = 0; j < 4; ++j) {
                const int row = gr0 + m * 16 + fq * 4 + j;
                Out[((size_t)e * MROWS + row) * NROWS + col] = acc[m][n][j] + bb;
            }
    }
}

// ---------------------------------------------------------------------------
extern "C" void kernel_launch(void* const* d_in, const int* in_sizes, int n_in,
                              void* d_out, int out_size, void* d_ws, size_t ws_size,
                              hipStream_t stream)
{
    const float* x  = (const float*)d_in[0];
    const float* w1 = (const float*)d_in[1];
    const float* b1 = (const float*)d_in[2];
    const float* w2 = (const float*)d_in[3];
    const float* b2 = (const float*)d_in[4];
    float* out = (float*)d_out;

    (void)hipFuncSetAttribute(reinterpret_cast<const void*>(&gemm256<M_, true>),
                              hipFuncAttributeMaxDynamicSharedMemorySize, 131072);
    (void)hipFuncSetAttribute(reinterpret_cast<const void*>(&gemm2tn),
                              hipFuncAttributeMaxDynamicSharedMemorySize, 131072);

    const size_t xb_sz  = (size_t)E_ * C_ * M_ * sizeof(bf16);   //  32 MB
    const size_t w1b_sz = (size_t)E_ * H_ * M_ * sizeof(bf16);   // 256 MB
    const size_t y1_sz  = (size_t)E_ * C_ * H_ * sizeof(bf16);   // 128 MB

    if (ws_size >= xb_sz + w1b_sz + y1_sz) {
        bf16* xb  = (bf16*)d_ws;
        bf16* w1b = (bf16*)((char*)d_ws + xb_sz);
        bf16* y1  = (bf16*)((char*)d_ws + xb_sz + w1b_sz);

        cvt_f32_bf16<<<2048, 256, 0, stream>>>(x,  xb,  (size_t)E_ * C_ * M_);
        cvt_f32_bf16<<<2048, 256, 0, stream>>>(w1, w1b, (size_t)E_ * H_ * M_);

        // gemm1: bf16 x bf16^T 8-phase (r3-proven), 1024 wgs
        gemm256<M_, true><<<dim3(8 * 4 * (H_ / 256)), 512, 131072, stream>>>(
            xb, w1b, b1, y1, 4, H_ / 256);
        // gemm2: TN — y1 bf16 x w2 native fp32 (in-register transpose staging)
        gemm2tn<<<dim3(8 * 4 * (O_ / 256)), 512, 131072, stream>>>(
            y1, w2, b2, out, 4, O_ / 256);
    } else {
        // per-expert fallback: 4 + 32 + 16 = 52 MB of ws
        bf16* xb  = (bf16*)d_ws;
        bf16* w1b = (bf16*)((char*)d_ws + xb_sz / E_);
        bf16* y1  = (bf16*)((char*)d_ws + (xb_sz + w1b_sz) / E_);
        for (int e = 0; e < E_; ++e) {
            cvt_f32_bf16<<<512, 256, 0, stream>>>(x + (size_t)e * C_ * M_,  xb,  (size_t)C_ * M_);
            cvt_f32_bf16<<<2048, 256, 0, stream>>>(w1 + (size_t)e * H_ * M_, w1b, (size_t)H_ * M_);
            gemm256<M_, true><<<dim3(4 * (H_ / 256)), 512, 131072, stream>>>(
                xb, w1b, b1 + (size_t)e * H_, y1, 4, H_ / 256);
            gemm2tn<<<dim3(4 * (O_ / 256)), 512, 131072, stream>>>(
                y1, w2 + (size_t)e * (size_t)H_ * O_, b2 + (size_t)e * O_,
                out + (size_t)e * C_ * O_, 4, O_ / 256);
        }
    }
}